// Round 6
// baseline (13419.815 us; speedup 1.0000x reference)
//
#include <hip/hip_runtime.h>

#define BB 128   // batch
#define SS 128   // seq
#define EE 256   // enc dim
#define DD 256   // lstm hidden
#define OO 64    // out dim

// bf16 weight buffer layout (ushort offsets) inside d_out scratch
#define W1_OFF   0         // 768*256   = 196608 (rows: Wh|Wc|We)
#define WHH_OFF  196608    // 256*1024  = 262144
#define WIH_OFF  458752    // 64*1024   = 65536
#define FCW_OFF  524288    // 320*64    = 20480
#define WTOTAL   544768

__device__ __forceinline__ float fsig(float x) { return 1.0f / (1.0f + __expf(-x)); }
__device__ __forceinline__ float ftanh(float x) {
    float t = __expf(-2.0f * fabsf(x));
    float r = (1.0f - t) / (1.0f + t);
    return copysignf(r, x);
}
// swizzle within 32-float groups: conflict-free strided access in P2
__device__ __forceinline__ int SWZ(int e) { return (e & ~31) | ((e + 4 * (e >> 5)) & 31); }

__device__ __forceinline__ unsigned short bf16r(float f) {
    unsigned int u = __float_as_uint(f);
    u = (u + 0x7fffu + ((u >> 16) & 1u)) >> 16;
    return (unsigned short)u;
}

__device__ __forceinline__ void fma8(const uint4 w, const float xv, float* acc) {
    acc[0] += xv * __uint_as_float(w.x << 16);
    acc[1] += xv * __uint_as_float(w.x & 0xffff0000u);
    acc[2] += xv * __uint_as_float(w.y << 16);
    acc[3] += xv * __uint_as_float(w.y & 0xffff0000u);
    acc[4] += xv * __uint_as_float(w.z << 16);
    acc[5] += xv * __uint_as_float(w.z & 0xffff0000u);
    acc[6] += xv * __uint_as_float(w.w << 16);
    acc[7] += xv * __uint_as_float(w.w & 0xffff0000u);
}

// fp32 -> bf16 (RNE) weight conversion, runs every launch (graph-safe, same work)
__global__ __launch_bounds__(256) void conv_kernel(
    const float* __restrict__ W1, const float* __restrict__ Whh,
    const float* __restrict__ Wih, const float* __restrict__ fcW,
    unsigned short* __restrict__ out)
{
    const int idx = blockIdx.x * 256 + threadIdx.x;
    float f;
    if      (idx < WHH_OFF)  f = W1[idx];
    else if (idx < WIH_OFF)  f = Whh[idx - WHH_OFF];
    else if (idx < FCW_OFF)  f = Wih[idx - WIH_OFF];
    else if (idx < WTOTAL)   f = fcW[idx - FCW_OFF];
    else return;
    out[idx] = bf16r(f);
}

// One block (1024 thr, 16 waves) per batch row; whole scan block-local.
// 9 barrier-phases per step; weight loads batched 8-16 deep for MLP.
__global__ __launch_bounds__(1024, 4) void scan_kernel(
    const float* __restrict__ inp,   // B,S,E
    const float* __restrict__ yhist, // B,S,OO
    const float* __restrict__ h0, const float* __restrict__ c0,
    const float* __restrict__ W1f,   // fp32 W1 (only We rows used, init)
    const float* __restrict__ b1, const float* __restrict__ w2, const float* __restrict__ b2,
    const float* __restrict__ bih, const float* __restrict__ bhh,
    const float* __restrict__ fcb,
    const unsigned short* __restrict__ wbf,  // bf16 weights (see *_OFF)
    float* __restrict__ hctxT)       // ws: [512][128] (0..255 h, 256..511 ctx)
{
    __shared__ float sh_h[DD], sh_c[DD], sh_hc[EE];      // sh_hc SWZ'd
    __shared__ float sh_gh[1024];
    __shared__ float sh_w2[EE];                          // SWZ'd
    __shared__ float sh_raw[SS];                         // exp(scores)
    __shared__ float sh_ctx[EE], sh_yt[OO], sh_y[OO];
    __shared__ float red1[32 * 256];                     // 32 KB
    __shared__ float red2[8 * 1024];                     // 32 KB

    const int b = blockIdx.x, t = threadIdx.x;
    const float* inp_b = inp + b * SS * EE;
    const unsigned short* W1bf  = wbf + W1_OFF;
    const unsigned short* Whhbf = wbf + WHH_OFF;
    const unsigned short* Wihbf = wbf + WIH_OFF;
    const unsigned short* fcWbf = wbf + FCW_OFF;
    const float b2v = b2[0];

    // per-thread constants
    const float b1_reg  = (t < 256) ? b1[t] : 0.f;
    const float fcb_reg = (t < 64) ? fcb[t] : 0.f;
    float bs4[4] = {0.f, 0.f, 0.f, 0.f};
    if (t < 256) {
        #pragma unroll
        for (int q = 0; q < 4; ++q) bs4[q] = bih[t + 256 * q] + bhh[t + 256 * q];
    }

    // role constants
    const int e8  = (t & 31) * 8,  kc1 = t >> 5;   // P1
    const int j8  = (t & 127) * 8, kc2 = t >> 7;   // P1b / P4
    const int s_own = t >> 3,      a2  = t & 7, e0 = a2 * 32;  // P2
    const int e4  = (t & 63) * 4,  sc  = t >> 6;   // P3
    const int o4  = (t & 15) * 4,  kc3 = t >> 4;   // P3b

    if (t < 256) {
        sh_h[t] = h0[b * 256 + t]; sh_c[t] = c0[b * 256 + t];
        sh_w2[SWZ(t)] = w2[t];
    }

    // ---- enc_proj into registers via LDS-staged chunks (fp32 We, one-time) ----
    float er[32];
    #pragma unroll
    for (int j = 0; j < 32; ++j) er[j] = 0.f;
    {
        const float* We = W1f + 512 * 256;
        for (int kc = 0; kc < 16; ++kc) {
            {   // stage We rows [kc*16,+16) x 256 -> red1[0..4095]
                const int row = t >> 6, c4 = (t & 63) * 4;
                float4 v = *(const float4*)(We + (size_t)(kc * 16 + row) * 256 + c4);
                *(float4*)&red1[row * 256 + c4] = v;
            }
            {   // stage inp cols [kc*16,+16) for all 128 s -> red1[4096..6143]
                const int s = t >> 3, k2 = (t & 7) * 2;
                float2 v = *(const float2*)(inp_b + s * 256 + kc * 16 + k2);
                red1[4096 + s * 16 + k2] = v.x;
                red1[4096 + s * 16 + k2 + 1] = v.y;
            }
            __syncthreads();
            for (int k = 0; k < 16; ++k) {
                const float xv = red1[4096 + s_own * 16 + k];
                #pragma unroll
                for (int j4 = 0; j4 < 8; ++j4) {
                    float4 w = *(const float4*)&red1[k * 256 + e0 + j4 * 4];
                    er[j4*4+0] += xv * w.x; er[j4*4+1] += xv * w.y;
                    er[j4*4+2] += xv * w.z; er[j4*4+3] += xv * w.w;
                }
            }
            __syncthreads();
        }
    }

    for (int ts = 0; ts < SS; ++ts) {
        if (t < 64) sh_y[t] = yhist[b * SS * OO + ts * OO + t];

        // ---- P1: hc partials [32][256] -> red1 (16 loads in flight)
        {
            uint4 w[16];
            #pragma unroll
            for (int i = 0; i < 16; ++i)
                w[i] = *(const uint4*)(W1bf + (size_t)(kc1 * 16 + i) * 256 + e8);
            float acc[8];
            #pragma unroll
            for (int r = 0; r < 8; ++r) acc[r] = 0.f;
            #pragma unroll
            for (int i = 0; i < 16; ++i) {
                const int k = kc1 * 16 + i;
                const float xv = (k < 256) ? sh_h[k] : sh_c[k - 256];
                fma8(w[i], xv, acc);
            }
            *(float4*)&red1[kc1 * 256 + e8]     = make_float4(acc[0], acc[1], acc[2], acc[3]);
            *(float4*)&red1[kc1 * 256 + e8 + 4] = make_float4(acc[4], acc[5], acc[6], acc[7]);
        }
        // ---- P1b: gh partials [8][1024] -> red2 (2 batches of 16)
        {
            float acc[8];
            #pragma unroll
            for (int r = 0; r < 8; ++r) acc[r] = 0.f;
            #pragma unroll
            for (int h2 = 0; h2 < 2; ++h2) {
                uint4 w[16];
                #pragma unroll
                for (int i = 0; i < 16; ++i)
                    w[i] = *(const uint4*)(Whhbf + (size_t)(kc2 * 32 + h2 * 16 + i) * 1024 + j8);
                #pragma unroll
                for (int i = 0; i < 16; ++i)
                    fma8(w[i], sh_h[kc2 * 32 + h2 * 16 + i], acc);
            }
            *(float4*)&red2[kc2 * 1024 + j8]     = make_float4(acc[0], acc[1], acc[2], acc[3]);
            *(float4*)&red2[kc2 * 1024 + j8 + 4] = make_float4(acc[4], acc[5], acc[6], acc[7]);
        }
        __syncthreads();   // B1

        // ---- reduce: hc (t<256) and gh (all t)
        if (t < 256) {
            float v = b1_reg;
            #pragma unroll 8
            for (int kc = 0; kc < 32; ++kc) v += red1[kc * 256 + t];
            sh_hc[SWZ(t)] = v;
        }
        {
            float v = 0.f;
            #pragma unroll
            for (int kc = 0; kc < 8; ++kc) v += red2[kc * 1024 + t];
            sh_gh[t] = v;
        }
        __syncthreads();   // B2

        // ---- P2: scores from register er + swizzled hc/w2 (conflict-free)
        {
            float acc = 0.f;
            #pragma unroll
            for (int j4 = 0; j4 < 8; ++j4) {
                const int phys = e0 + ((j4 * 4 + 4 * a2) & 31);
                float4 hc4 = *(const float4*)&sh_hc[phys];
                float4 w24 = *(const float4*)&sh_w2[phys];
                acc += ftanh(er[j4*4+0] + hc4.x) * w24.x;
                acc += ftanh(er[j4*4+1] + hc4.y) * w24.y;
                acc += ftanh(er[j4*4+2] + hc4.z) * w24.z;
                acc += ftanh(er[j4*4+3] + hc4.w) * w24.w;
            }
            acc += __shfl_xor(acc, 1);
            acc += __shfl_xor(acc, 2);
            acc += __shfl_xor(acc, 4);
            if (a2 == 0) sh_raw[s_own] = __expf(acc + b2v);  // max-free: |score|<=sum|w2|~10
        }
        __syncthreads();   // B3

        // ---- P3: context partials [16][256] -> red1 (global fp32 inp)
        {
            float ax = 0.f, ay = 0.f, az = 0.f, aw = 0.f;
            for (int s = sc * 8; s < sc * 8 + 8; ++s) {
                const float al = sh_raw[s];
                float4 iv = *(const float4*)(inp_b + s * 256 + e4);
                ax += al * iv.x; ay += al * iv.y; az += al * iv.z; aw += al * iv.w;
            }
            *(float4*)&red1[sc * 256 + e4] = make_float4(ax, ay, az, aw);
        }
        __syncthreads();   // B4

        // ---- ctx reduce (t<256) with per-wave redundant softmax denominator
        if (t < 256) {
            const int lane = t & 63;
            float sm = sh_raw[lane] + sh_raw[64 + lane];
            #pragma unroll
            for (int m = 32; m > 0; m >>= 1) sm += __shfl_xor(sm, m);
            const float rs = 1.0f / sm;
            float v = 0.f;
            #pragma unroll
            for (int k = 0; k < 16; ++k) v += red1[k * 256 + t];
            v *= rs;
            sh_ctx[t] = v;
            if (ts == SS - 1) hctxT[(size_t)(256 + t) * 128 + b] = v;
        }
        __syncthreads();   // B5

        // ---- P3b: y_tilde partials [64][64] -> red1 (5 loads in flight)
        {
            uint2 w[5];
            #pragma unroll
            for (int i = 0; i < 5; ++i)
                w[i] = *(const uint2*)(fcWbf + (kc3 * 5 + i) * 64 + o4);
            float acc[4] = {0.f, 0.f, 0.f, 0.f};
            #pragma unroll
            for (int i = 0; i < 5; ++i) {
                const int kk = kc3 * 5 + i;
                const float val = (kk < 256) ? sh_ctx[kk] : sh_y[kk - 256];
                acc[0] += val * __uint_as_float(w[i].x << 16);
                acc[1] += val * __uint_as_float(w[i].x & 0xffff0000u);
                acc[2] += val * __uint_as_float(w[i].y << 16);
                acc[3] += val * __uint_as_float(w[i].y & 0xffff0000u);
            }
            *(float4*)&red1[kc3 * 64 + o4] = make_float4(acc[0], acc[1], acc[2], acc[3]);
        }
        __syncthreads();   // B6

        if (t < 64) {
            float v = fcb_reg;
            #pragma unroll 16
            for (int kc = 0; kc < 64; ++kc) v += red1[kc * 64 + t];
            sh_yt[t] = v;
        }
        __syncthreads();   // B7

        // ---- P4: gate partials (Wih) [8][1024] -> red2 (8 loads in flight)
        {
            uint4 w[8];
            #pragma unroll
            for (int i = 0; i < 8; ++i)
                w[i] = *(const uint4*)(Wihbf + (size_t)(kc2 * 8 + i) * 1024 + j8);
            float acc[8];
            #pragma unroll
            for (int r = 0; r < 8; ++r) acc[r] = 0.f;
            #pragma unroll
            for (int i = 0; i < 8; ++i)
                fma8(w[i], sh_yt[kc2 * 8 + i], acc);
            *(float4*)&red2[kc2 * 1024 + j8]     = make_float4(acc[0], acc[1], acc[2], acc[3]);
            *(float4*)&red2[kc2 * 1024 + j8 + 4] = make_float4(acc[4], acc[5], acc[6], acc[7]);
        }
        __syncthreads();   // B8

        // ---- fused gates reduce + LSTM pointwise (t<256)
        if (t < 256) {
            float g[4];
            #pragma unroll
            for (int q = 0; q < 4; ++q) {
                float v = sh_gh[t + 256 * q] + bs4[q];
                #pragma unroll
                for (int kc = 0; kc < 8; ++kc) v += red2[kc * 1024 + t + 256 * q];
                g[q] = v;
            }
            const float cn = fsig(g[1]) * sh_c[t] + fsig(g[0]) * ftanh(g[2]);
            sh_c[t] = cn;
            const float hn = fsig(g[3]) * ftanh(cn);
            sh_h[t] = hn;
            if (ts == SS - 1) hctxT[(size_t)t * 128 + b] = hn;
        }
        __syncthreads();   // B9
    }
}

// out(128 x 8192) = A(128x512, stored transposed AT[512][128]) @ W(512x8192) + bias
__global__ __launch_bounds__(256) void out_gemm(
    const float* __restrict__ AT, const float* __restrict__ W,
    const float* __restrict__ bias, float* __restrict__ out)
{
    __shared__ float Ab[64 * 132];  // [k][m]
    __shared__ float Bb[64 * 32];   // [k][n]
    const int t = threadIdx.x;
    const int nt = blockIdx.x * 32;
    const int n4 = (t & 7) * 4;
    const int m4 = (t >> 3) * 4;
    float acc[4][4];
    #pragma unroll
    for (int i = 0; i < 4; ++i)
        #pragma unroll
        for (int jj = 0; jj < 4; ++jj) acc[i][jj] = 0.f;

    for (int kc = 0; kc < 8; ++kc) {
        #pragma unroll
        for (int i = 0; i < 8; ++i) {
            const int flat4 = i * 256 + t;
            const int row = flat4 >> 5, mm4 = (flat4 & 31) * 4;
            float4 v = *(const float4*)(AT + (size_t)(kc * 64 + row) * 128 + mm4);
            *(float4*)&Ab[row * 132 + mm4] = v;
        }
        #pragma unroll
        for (int i = 0; i < 2; ++i) {
            const int fl = t + i * 256;
            const int k = fl >> 3, nn4 = (fl & 7) * 4;
            *(float4*)&Bb[k * 32 + nn4] =
                *(const float4*)(W + (size_t)(kc * 64 + k) * 8192 + nt + nn4);
        }
        __syncthreads();
        for (int k = 0; k < 64; ++k) {
            const float4 bv = *(const float4*)&Bb[k * 32 + n4];
            const float4 av = *(const float4*)&Ab[k * 132 + m4];
            acc[0][0] += av.x * bv.x; acc[0][1] += av.x * bv.y; acc[0][2] += av.x * bv.z; acc[0][3] += av.x * bv.w;
            acc[1][0] += av.y * bv.x; acc[1][1] += av.y * bv.y; acc[1][2] += av.y * bv.z; acc[1][3] += av.y * bv.w;
            acc[2][0] += av.z * bv.x; acc[2][1] += av.z * bv.y; acc[2][2] += av.z * bv.z; acc[2][3] += av.z * bv.w;
            acc[3][0] += av.w * bv.x; acc[3][1] += av.w * bv.y; acc[3][2] += av.w * bv.z; acc[3][3] += av.w * bv.w;
        }
        __syncthreads();
    }
    const float4 bb = *(const float4*)(bias + nt + n4);
    #pragma unroll
    for (int i = 0; i < 4; ++i) {
        float4 r;
        r.x = acc[i][0] + bb.x; r.y = acc[i][1] + bb.y;
        r.z = acc[i][2] + bb.z; r.w = acc[i][3] + bb.w;
        *(float4*)(out + (size_t)(m4 + i) * 8192 + nt + n4) = r;
    }
}

extern "C" void kernel_launch(void* const* d_in, const int* in_sizes, int n_in,
                              void* d_out, int out_size, void* d_ws, size_t ws_size,
                              hipStream_t stream) {
    const float* inp = (const float*)d_in[0];
    const float* yh  = (const float*)d_in[1];
    const float* h0  = (const float*)d_in[2];
    const float* c0  = (const float*)d_in[3];
    const float* W1  = (const float*)d_in[4];
    const float* b1  = (const float*)d_in[5];
    const float* w2  = (const float*)d_in[6];
    const float* b2  = (const float*)d_in[7];
    const float* Wih = (const float*)d_in[8];
    const float* Whh = (const float*)d_in[9];
    const float* bih = (const float*)d_in[10];
    const float* bhh = (const float*)d_in[11];
    const float* fcW = (const float*)d_in[12];
    const float* fcb = (const float*)d_in[13];
    const float* foW = (const float*)d_in[14];
    const float* fob = (const float*)d_in[15];

    float* hctxT = (float*)d_ws;                    // 256 KB (proven)
    unsigned short* wbf = (unsigned short*)d_out;   // 1.09 MB bf16 weights in d_out scratch
                                                    // (fully overwritten by out_gemm)

    conv_kernel<<<dim3((WTOTAL + 255) / 256), dim3(256), 0, stream>>>(W1, Whh, Wih, fcW, wbf);
    scan_kernel<<<dim3(BB), dim3(1024), 0, stream>>>(
        inp, yh, h0, c0, W1, b1, w2, b2, bih, bhh, fcb, wbf, hctxT);
    out_gemm<<<dim3(8192 / 32), dim3(256), 0, stream>>>(hctxT, foW, fob, (float*)d_out);
}

// Round 7
// 6180.969 us; speedup vs baseline: 2.1712x; 2.1712x over previous
//
#include <hip/hip_runtime.h>

#define BB 128   // batch
#define SS 128   // seq
#define EE 256   // enc dim
#define DD 256   // lstm hidden
#define OO 64    // out dim

// bf16 weight buffer layout (ushort offsets) inside d_out scratch
#define W1_OFF   0         // 768*256   = 196608 (rows: Wh|Wc|We)
#define WHH_OFF  196608    // 256*1024  = 262144
#define WIH_OFF  458752    // 64*1024   = 65536
#define FCW_OFF  524288    // 320*64    = 20480
#define WTOTAL   544768

__device__ __forceinline__ float fsig(float x) { return 1.0f / (1.0f + __expf(-x)); }
__device__ __forceinline__ float ftanh(float x) {
    float t = __expf(-2.0f * fabsf(x));
    float r = (1.0f - t) / (1.0f + t);
    return copysignf(r, x);
}
// swizzle within 32-float groups: conflict-free strided access in P2
__device__ __forceinline__ int SWZ(int e) { return (e & ~31) | ((e + 4 * (e >> 5)) & 31); }

__device__ __forceinline__ unsigned short bf16r(float f) {
    unsigned int u = __float_as_uint(f);
    u = (u + 0x7fffu + ((u >> 16) & 1u)) >> 16;
    return (unsigned short)u;
}
__device__ __forceinline__ float bflo(unsigned int x) { return __uint_as_float(x << 16); }
__device__ __forceinline__ float bfhi(unsigned int x) { return __uint_as_float(x & 0xffff0000u); }

// async global->LDS DMA, 16 B per lane (wave moves 1 KB contiguous)
__device__ __forceinline__ void dma16(const unsigned short* g, unsigned short* l) {
    __builtin_amdgcn_global_load_lds(
        (const __attribute__((address_space(1))) unsigned int*)g,
        (__attribute__((address_space(3))) unsigned int*)l, 16, 0, 0);
}

// fp32 -> bf16 (RNE) weight conversion, runs every launch (graph-safe, same work)
__global__ __launch_bounds__(256) void conv_kernel(
    const float* __restrict__ W1, const float* __restrict__ Whh,
    const float* __restrict__ Wih, const float* __restrict__ fcW,
    unsigned short* __restrict__ out)
{
    const int idx = blockIdx.x * 256 + threadIdx.x;
    float f;
    if      (idx < WHH_OFF)  f = W1[idx];
    else if (idx < WIH_OFF)  f = Whh[idx - WHH_OFF];
    else if (idx < FCW_OFF)  f = Wih[idx - WIH_OFF];
    else if (idx < WTOTAL)   f = fcW[idx - FCW_OFF];
    else return;
    out[idx] = bf16r(f);
}

// One block (1024 thr, 16 waves) per batch row; whole scan block-local.
// W1+Whh stream L2->LDS via double-buffered global_load_lds (12 x 64KB chunks/step).
__global__ __launch_bounds__(1024, 4) void scan_kernel(
    const float* __restrict__ inp,   // B,S,E
    const float* __restrict__ yhist, // B,S,OO
    const float* __restrict__ h0, const float* __restrict__ c0,
    const float* __restrict__ W1f,   // fp32 W1 (only We rows used, init)
    const float* __restrict__ b1, const float* __restrict__ w2, const float* __restrict__ b2,
    const float* __restrict__ bih, const float* __restrict__ bhh,
    const float* __restrict__ fcb,
    const unsigned short* __restrict__ wbf,  // bf16 weights (see *_OFF)
    float* __restrict__ hctxT)       // ws: [512][128] (0..255 h, 256..511 ctx)
{
    __shared__ unsigned short buf[2][32768];  // 2 x 64 KB weight chunks
    __shared__ float red[5152];               // partials [<=4096] | gates [4096..5119] | misc [5120]
    __shared__ float sh_h[DD], sh_c[DD], sh_hc[EE];  // sh_hc SWZ'd
    __shared__ float sh_w2[EE];                      // SWZ'd
    __shared__ float sh_raw[SS];
    __shared__ float sh_ctx[EE], sh_yt[OO], sh_y[OO];

    const int b = blockIdx.x, t = threadIdx.x;
    const int lane = t & 63, wv = t >> 6;
    const float* inp_b = inp + b * SS * EE;
    const unsigned short* Wihbf = wbf + WIH_OFF;
    const unsigned short* fcWbf = wbf + FCW_OFF;
    const float b2v = b2[0];

    // per-thread constants
    const float bs_reg  = bih[t] + bhh[t];
    const float b1_reg  = (t < 256) ? b1[t] : 0.f;
    const float fcb_reg = (t < 64) ? fcb[t] : 0.f;

    // role constants
    const int e4p = (t & 63) * 4,  kc1 = t >> 6;   // P1   (16 windows of 8k per chunk)
    const int j4  = (t & 255) * 4, kcb = t >> 8;   // P1b / P4 (4 windows)
    const int s_own = t >> 3,      a2  = t & 7, e0 = a2 * 32;  // P2
    const int e4  = (t & 63) * 4,  sc  = t >> 6;   // P3
    const int o4  = (t & 15) * 4,  kc3 = t >> 4;   // P3b

    if (t < 256) {
        sh_h[t] = h0[b * 256 + t]; sh_c[t] = c0[b * 256 + t];
        sh_w2[SWZ(t)] = w2[t];
    }

    // ---- enc_proj into registers via LDS-staged chunks (fp32 We, one-time) ----
    // stages into buf area (free before weight DMA starts)
    float er[32];
    #pragma unroll
    for (int j = 0; j < 32; ++j) er[j] = 0.f;
    {
        float* stg = (float*)&buf[0][0];     // We [16][256] at 0, il [128][16] at 4096
        const float* We = W1f + 512 * 256;
        for (int kc = 0; kc < 16; ++kc) {
            {
                const int row = t >> 6, c4 = (t & 63) * 4;
                float4 v = *(const float4*)(We + (size_t)(kc * 16 + row) * 256 + c4);
                *(float4*)&stg[row * 256 + c4] = v;
            }
            {
                const int s = t >> 3, k2 = (t & 7) * 2;
                float2 v = *(const float2*)(inp_b + s * 256 + kc * 16 + k2);
                stg[4096 + s * 16 + k2]     = v.x;
                stg[4096 + s * 16 + k2 + 1] = v.y;
            }
            __syncthreads();
            for (int k = 0; k < 16; ++k) {
                const float xv = stg[4096 + s_own * 16 + k];
                #pragma unroll
                for (int j4i = 0; j4i < 8; ++j4i) {
                    float4 w = *(const float4*)&stg[k * 256 + e0 + j4i * 4];
                    er[j4i*4+0] += xv * w.x; er[j4i*4+1] += xv * w.y;
                    er[j4i*4+2] += xv * w.z; er[j4i*4+3] += xv * w.w;
                }
            }
            __syncthreads();
        }
    }

    // ---- preload weight chunk 0 (W1 rows 0..127) into buf[0] ----
    #pragma unroll
    for (int q = 0; q < 4; ++q) {
        const int r1k = q * 16 + wv;
        dma16(wbf + (size_t)r1k * 512 + lane * 8, &buf[0][r1k * 512]);
    }
    __syncthreads();

    for (int ts = 0; ts < SS; ++ts) {
        if (t < 64) sh_y[t] = yhist[b * SS * OO + ts * OO + t];

        // ================= P1: hc partials over 4 W1 chunks =================
        float acc1[4] = {0.f, 0.f, 0.f, 0.f};
        for (int m = 0; m < 4; ++m) {
            // issue DMA for next chunk (m+1<4: W1 chunk m+1; m==3: Whh chunk 0)
            {
                const size_t src = (m < 3) ? (size_t)(m + 1) * 32768 : (size_t)WHH_OFF;
                const int pb = (m + 1) & 1;
                #pragma unroll
                for (int q = 0; q < 4; ++q) {
                    const int r1k = q * 16 + wv;
                    dma16(wbf + src + (size_t)r1k * 512 + lane * 8, &buf[pb][r1k * 512]);
                }
            }
            // compute from buf[m&1]: chunk = W1 rows [128m, 128m+128)
            const unsigned short* base = &buf[m & 1][0];
            #pragma unroll
            for (int i = 0; i < 8; ++i) {
                const int kloc = kc1 * 8 + i;
                const int kglob = m * 128 + kloc;
                const float xv = (kglob < 256) ? sh_h[kglob] : sh_c[kglob - 256];
                uint2 wvv = *(const uint2*)(base + kloc * 256 + e4p);
                acc1[0] += xv * bflo(wvv.x); acc1[1] += xv * bfhi(wvv.x);
                acc1[2] += xv * bflo(wvv.y); acc1[3] += xv * bfhi(wvv.y);
            }
            if (m == 3)
                *(float4*)&red[kc1 * 256 + e4p] = make_float4(acc1[0], acc1[1], acc1[2], acc1[3]);
            __syncthreads();
        }

        // ================= P1b: gh partials over 8 Whh chunks =================
        float acc2[4] = {0.f, 0.f, 0.f, 0.f};
        for (int n = 0; n < 8; ++n) {
            // issue DMA for next chunk (n<7: Whh n+1; n==7: W1 chunk 0 for next step)
            {
                const size_t src = (n < 7) ? (size_t)WHH_OFF + (size_t)(n + 1) * 32768 : 0;
                const int pb = (n + 1) & 1;
                #pragma unroll
                for (int q = 0; q < 4; ++q) {
                    const int r1k = q * 16 + wv;
                    dma16(wbf + src + (size_t)r1k * 512 + lane * 8, &buf[pb][r1k * 512]);
                }
            }
            if (n == 0 && t < 256) {   // hc reduce (red1 written pre-barrier in m==3)
                float v = b1_reg;
                #pragma unroll
                for (int kc = 0; kc < 16; ++kc) v += red[kc * 256 + t];
                sh_hc[SWZ(t)] = v;
            }
            // compute from buf[n&1]: chunk = Whh rows [32n, 32n+32)
            const unsigned short* base = &buf[n & 1][0];
            #pragma unroll
            for (int i = 0; i < 8; ++i) {
                const int kloc = kcb * 8 + i;
                const float xv = sh_h[n * 32 + kloc];
                uint2 wvv = *(const uint2*)(base + kloc * 1024 + j4);
                acc2[0] += xv * bflo(wvv.x); acc2[1] += xv * bfhi(wvv.x);
                acc2[2] += xv * bflo(wvv.y); acc2[3] += xv * bfhi(wvv.y);
            }
            if (n == 7)
                *(float4*)&red[kcb * 1024 + j4] = make_float4(acc2[0], acc2[1], acc2[2], acc2[3]);
            __syncthreads();
        }

        // ---- gh reduce (register) + P2 scores ----
        float gh_reg = 0.f;
        #pragma unroll
        for (int kc = 0; kc < 4; ++kc) gh_reg += red[kc * 1024 + t];
        {
            float acc = 0.f;
            #pragma unroll
            for (int j4i = 0; j4i < 8; ++j4i) {
                const int phys = e0 + ((j4i * 4 + 4 * a2) & 31);
                float4 hc4 = *(const float4*)&sh_hc[phys];
                float4 w24 = *(const float4*)&sh_w2[phys];
                acc += ftanh(er[j4i*4+0] + hc4.x) * w24.x;
                acc += ftanh(er[j4i*4+1] + hc4.y) * w24.y;
                acc += ftanh(er[j4i*4+2] + hc4.z) * w24.z;
                acc += ftanh(er[j4i*4+3] + hc4.w) * w24.w;
            }
            acc += __shfl_xor(acc, 1);
            acc += __shfl_xor(acc, 2);
            acc += __shfl_xor(acc, 4);
            if (a2 == 0) sh_raw[s_own] = __expf(acc + b2v);  // max-free: |score|<=sum|w2|~10
        }
        __syncthreads();
        if (t < 64) {
            float v = sh_raw[t] + sh_raw[t + 64];
            #pragma unroll
            for (int m = 32; m > 0; m >>= 1) v += __shfl_xor(v, m);
            if (t == 0) red[5120] = 1.0f / v;
        }
        __syncthreads();

        // ---- P3: context partials [16][256] (global fp32 inp) ----
        {
            float ax = 0.f, ay = 0.f, az = 0.f, aw = 0.f;
            for (int s = sc * 8; s < sc * 8 + 8; ++s) {
                const float al = sh_raw[s];
                float4 iv = *(const float4*)(inp_b + s * 256 + e4);
                ax += al * iv.x; ay += al * iv.y; az += al * iv.z; aw += al * iv.w;
            }
            *(float4*)&red[sc * 256 + e4] = make_float4(ax, ay, az, aw);
        }
        __syncthreads();
        if (t < 256) {
            float v = 0.f;
            #pragma unroll
            for (int k = 0; k < 16; ++k) v += red[k * 256 + t];
            v *= red[5120];
            sh_ctx[t] = v;
            if (ts == SS - 1) hctxT[(size_t)(256 + t) * 128 + b] = v;
        }
        __syncthreads();

        // ---- P3b: y_tilde partials [64][64] ----
        {
            float acc[4] = {0.f, 0.f, 0.f, 0.f};
            for (int kk = kc3 * 5; kk < kc3 * 5 + 5; ++kk) {
                const float val = (kk < 256) ? sh_ctx[kk] : sh_y[kk - 256];
                uint2 w = *(const uint2*)(fcWbf + kk * 64 + o4);
                acc[0] += val * bflo(w.x); acc[1] += val * bfhi(w.x);
                acc[2] += val * bflo(w.y); acc[3] += val * bfhi(w.y);
            }
            *(float4*)&red[kc3 * 64 + o4] = make_float4(acc[0], acc[1], acc[2], acc[3]);
        }
        __syncthreads();
        if (t < 64) {
            float v = fcb_reg;
            #pragma unroll 16
            for (int kc = 0; kc < 64; ++kc) v += red[kc * 64 + t];
            sh_yt[t] = v;
        }
        __syncthreads();

        // ---- P4: gate partials (Wih direct global) [4][1024] ----
        {
            float acc[4] = {0.f, 0.f, 0.f, 0.f};
            #pragma unroll 4
            for (int k = kcb * 16; k < kcb * 16 + 16; ++k) {
                const float yv = sh_yt[k];
                uint2 w = *(const uint2*)(Wihbf + (size_t)k * 1024 + j4);
                acc[0] += yv * bflo(w.x); acc[1] += yv * bfhi(w.x);
                acc[2] += yv * bflo(w.y); acc[3] += yv * bfhi(w.y);
            }
            *(float4*)&red[kcb * 1024 + j4] = make_float4(acc[0], acc[1], acc[2], acc[3]);
        }
        __syncthreads();

        // ---- gates reduce -> red[4096..5119] ----
        {
            float v = gh_reg + bs_reg;
            #pragma unroll
            for (int kc = 0; kc < 4; ++kc) v += red[kc * 1024 + t];
            red[4096 + t] = v;
        }
        __syncthreads();
        if (t < 256) {
            const float gi = red[4096 + t],       gf = red[4096 + 256 + t];
            const float gg = red[4096 + 512 + t], go = red[4096 + 768 + t];
            const float cn = fsig(gf) * sh_c[t] + fsig(gi) * ftanh(gg);
            sh_c[t] = cn;
            const float hn = fsig(go) * ftanh(cn);
            sh_h[t] = hn;
            if (ts == SS - 1) hctxT[(size_t)t * 128 + b] = hn;
        }
        __syncthreads();
    }
}

// out(128 x 8192) = A(128x512, stored transposed AT[512][128]) @ W(512x8192) + bias
__global__ __launch_bounds__(256) void out_gemm(
    const float* __restrict__ AT, const float* __restrict__ W,
    const float* __restrict__ bias, float* __restrict__ out)
{
    __shared__ float Ab[64 * 132];  // [k][m]
    __shared__ float Bb[64 * 32];   // [k][n]
    const int t = threadIdx.x;
    const int nt = blockIdx.x * 32;
    const int n4 = (t & 7) * 4;
    const int m4 = (t >> 3) * 4;
    float acc[4][4];
    #pragma unroll
    for (int i = 0; i < 4; ++i)
        #pragma unroll
        for (int jj = 0; jj < 4; ++jj) acc[i][jj] = 0.f;

    for (int kc = 0; kc < 8; ++kc) {
        #pragma unroll
        for (int i = 0; i < 8; ++i) {
            const int flat4 = i * 256 + t;
            const int row = flat4 >> 5, mm4 = (flat4 & 31) * 4;
            float4 v = *(const float4*)(AT + (size_t)(kc * 64 + row) * 128 + mm4);
            *(float4*)&Ab[row * 132 + mm4] = v;
        }
        #pragma unroll
        for (int i = 0; i < 2; ++i) {
            const int fl = t + i * 256;
            const int k = fl >> 3, nn4 = (fl & 7) * 4;
            *(float4*)&Bb[k * 32 + nn4] =
                *(const float4*)(W + (size_t)(kc * 64 + k) * 8192 + nt + nn4);
        }
        __syncthreads();
        for (int k = 0; k < 64; ++k) {
            const float4 bv = *(const float4*)&Bb[k * 32 + n4];
            const float4 av = *(const float4*)&Ab[k * 132 + m4];
            acc[0][0] += av.x * bv.x; acc[0][1] += av.x * bv.y; acc[0][2] += av.x * bv.z; acc[0][3] += av.x * bv.w;
            acc[1][0] += av.y * bv.x; acc[1][1] += av.y * bv.y; acc[1][2] += av.y * bv.z; acc[1][3] += av.y * bv.w;
            acc[2][0] += av.z * bv.x; acc[2][1] += av.z * bv.y; acc[2][2] += av.z * bv.z; acc[2][3] += av.z * bv.w;
            acc[3][0] += av.w * bv.x; acc[3][1] += av.w * bv.y; acc[3][2] += av.w * bv.z; acc[3][3] += av.w * bv.w;
        }
        __syncthreads();
    }
    const float4 bb = *(const float4*)(bias + nt + n4);
    #pragma unroll
    for (int i = 0; i < 4; ++i) {
        float4 r;
        r.x = acc[i][0] + bb.x; r.y = acc[i][1] + bb.y;
        r.z = acc[i][2] + bb.z; r.w = acc[i][3] + bb.w;
        *(float4*)(out + (size_t)(m4 + i) * 8192 + nt + n4) = r;
    }
}

extern "C" void kernel_launch(void* const* d_in, const int* in_sizes, int n_in,
                              void* d_out, int out_size, void* d_ws, size_t ws_size,
                              hipStream_t stream) {
    const float* inp = (const float*)d_in[0];
    const float* yh  = (const float*)d_in[1];
    const float* h0  = (const float*)d_in[2];
    const float* c0  = (const float*)d_in[3];
    const float* W1  = (const float*)d_in[4];
    const float* b1  = (const float*)d_in[5];
    const float* w2  = (const float*)d_in[6];
    const float* b2  = (const float*)d_in[7];
    const float* Wih = (const float*)d_in[8];
    const float* Whh = (const float*)d_in[9];
    const float* bih = (const float*)d_in[10];
    const float* bhh = (const float*)d_in[11];
    const float* fcW = (const float*)d_in[12];
    const float* fcb = (const float*)d_in[13];
    const float* foW = (const float*)d_in[14];
    const float* fob = (const float*)d_in[15];

    float* hctxT = (float*)d_ws;                    // 256 KB (proven)
    unsigned short* wbf = (unsigned short*)d_out;   // 1.09 MB bf16 weights in d_out scratch
                                                    // (fully overwritten by out_gemm)

    conv_kernel<<<dim3((WTOTAL + 255) / 256), dim3(256), 0, stream>>>(W1, Whh, Wih, fcW, wbf);
    scan_kernel<<<dim3(BB), dim3(1024), 0, stream>>>(
        inp, yh, h0, c0, W1, b1, w2, b2, bih, bhh, fcb, wbf, hctxT);
    out_gemm<<<dim3(8192 / 32), dim3(256), 0, stream>>>(hctxT, foW, fob, (float*)d_out);
}